// Round 3
// baseline (23.660 us; speedup 1.0000x reference)
//
#include <hip/hip_runtime.h>

// DiagonalSSM: out[d,h,l] = 2*Re( sum_n sc[d,h,n] * exp(delta_a[h,n]*l) )
// H=1024, N=32, L=2048, D=2.
//
// R2: two-term REAL recurrence. For each mode, g_k = Re(sc * z^(l0+128k))
// satisfies g_{k+2} = p*g_{k+1} - m*g_k with p = 2*Re(q128), m = |q128|^2,
// q128 = exp(delta_a*128). 2 VALU ops per point-mode instead of a 4-FMA
// complex multiply; accumulate directly (no tmp copy).

#define H_DIM 1024
#define N_DIM 32
#define L_DIM 2048
#define STRIDE 128
#define ITERS (L_DIM / STRIDE)   // 16

__global__ __launch_bounds__(256) void DiagonalSSMKernel_18769007084374_kernel(
    const float* __restrict__ log_dt,
    const float* __restrict__ log_a_real,
    const float* __restrict__ a_imag,
    const float* __restrict__ coeffs,
    float* __restrict__ out)
{
    __shared__ float s_dar[N_DIM], s_dai[N_DIM];          // delta_a
    __shared__ float s_qr[N_DIM], s_qi[N_DIM];            // q128 = exp(delta_a*128)
    __shared__ float s_p[N_DIM], s_m[N_DIM];              // recurrence coeffs
    __shared__ float s_scr[2][N_DIM], s_sci[2][N_DIM];    // 2*c*(exp(da)-1)/a

    const int h = blockIdx.x;
    const int tid = threadIdx.x;

    if (tid < N_DIM) {
        const int n = tid;
        const float dt  = __expf(log_dt[h]);
        const float arl = -__expf(log_a_real[h * N_DIM + n]);   // Re(a)
        const float aim = a_imag[h * N_DIM + n];                // Im(a)
        const float dar = arl * dt;
        const float dai = aim * dt;

        // f = (exp(delta_a) - 1) / a
        const float er = __expf(dar);
        float si1, co1;
        __sincosf(dai, &si1, &co1);
        const float num_r = er * co1 - 1.0f;
        const float num_i = er * si1;
        const float inv_den = 1.0f / (arl * arl + aim * aim);
        const float f_r = (num_r * arl + num_i * aim) * inv_den;
        const float f_i = (num_i * arl - num_r * aim) * inv_den;

        #pragma unroll
        for (int d = 0; d < 2; ++d) {
            const float cr = coeffs[((d * H_DIM + h) * N_DIM + n) * 2 + 0];
            const float ci = coeffs[((d * H_DIM + h) * N_DIM + n) * 2 + 1];
            s_scr[d][n] = 2.0f * (cr * f_r - ci * f_i);
            s_sci[d][n] = 2.0f * (cr * f_i + ci * f_r);
        }

        s_dar[n] = dar;
        s_dai[n] = dai;

        // q128 = exp(delta_a * STRIDE); recurrence coeffs
        const float wq = __expf(dar * (float)STRIDE);
        float sq, cq;
        __sincosf(dai * (float)STRIDE, &sq, &cq);
        const float qr = wq * cq;
        const float qi = wq * sq;
        s_qr[n] = qr;
        s_qi[n] = qi;
        s_p[n]  = 2.0f * qr;
        s_m[n]  = wq * wq;          // |q128|^2
    }
    __syncthreads();

    const int d  = tid >> 7;      // direction
    const int l0 = tid & 127;     // lane offset within stride
    const float lf = (float)l0;

    float gA[N_DIM], gB[N_DIM], p[N_DIM], m[N_DIM];

    #pragma unroll
    for (int n = 0; n < N_DIM; ++n) {
        // z = exp(delta_a * l0)
        const float w = __expf(s_dar[n] * lf);
        float sn, cn;
        __sincosf(s_dai[n] * lf, &sn, &cn);
        const float zr = w * cn;
        const float zi = w * sn;
        // z2 = z * q128  -> value at l0 + 128
        const float qr = s_qr[n], qi = s_qi[n];
        const float z2r = zr * qr - zi * qi;
        const float z2i = zr * qi + zi * qr;
        const float cr = s_scr[d][n], ci = s_sci[d][n];
        gA[n] = cr * zr  - ci * zi;    // g_0
        gB[n] = cr * z2r - ci * z2i;   // g_1
        p[n] = s_p[n];
        m[n] = s_m[n];
    }

    float* outp = out + (size_t)d * H_DIM * L_DIM + (size_t)h * L_DIM + l0;

    #pragma unroll
    for (int k = 0; k < ITERS; k += 2) {
        // ---- even step: output sum(gA), then gA <- g_{k+2}
        {
            float a0 = 0.f, a1 = 0.f, a2 = 0.f, a3 = 0.f;
            #pragma unroll
            for (int n = 0; n < N_DIM; n += 4) {
                a0 += gA[n + 0];
                a1 += gA[n + 1];
                a2 += gA[n + 2];
                a3 += gA[n + 3];
            }
            outp[k * STRIDE] = (a0 + a1) + (a2 + a3);
        }
        if (k + 2 < ITERS) {
            #pragma unroll
            for (int n = 0; n < N_DIM; ++n) {
                const float t = m[n] * gA[n];
                gA[n] = fmaf(p[n], gB[n], -t);   // g_{k+2}
            }
        }
        // ---- odd step: output sum(gB), then gB <- g_{k+3}
        {
            float a0 = 0.f, a1 = 0.f, a2 = 0.f, a3 = 0.f;
            #pragma unroll
            for (int n = 0; n < N_DIM; n += 4) {
                a0 += gB[n + 0];
                a1 += gB[n + 1];
                a2 += gB[n + 2];
                a3 += gB[n + 3];
            }
            outp[(k + 1) * STRIDE] = (a0 + a1) + (a2 + a3);
        }
        if (k + 3 < ITERS) {
            #pragma unroll
            for (int n = 0; n < N_DIM; ++n) {
                const float t = m[n] * gB[n];
                gB[n] = fmaf(p[n], gA[n], -t);   // g_{k+3}
            }
        }
    }
}

extern "C" void kernel_launch(void* const* d_in, const int* in_sizes, int n_in,
                              void* d_out, int out_size, void* d_ws, size_t ws_size,
                              hipStream_t stream) {
    const float* log_dt     = (const float*)d_in[0];
    const float* log_a_real = (const float*)d_in[1];
    const float* a_imag     = (const float*)d_in[2];
    const float* coeffs     = (const float*)d_in[3];
    float* out = (float*)d_out;

    DiagonalSSMKernel_18769007084374_kernel<<<dim3(H_DIM), 256, 0, stream>>>(
        log_dt, log_a_real, a_imag, coeffs, out);
}